// Round 16
// baseline (48.181 us; speedup 1.0000x reference)
//
#include <hip/hip_runtime.h>
#include <math.h>

// Problem constants (fixed by the reference)
#define Bn   32
#define Qn   900
#define Cn   92
#define WPB  4                   // waves per block
#define RW   5                   // rows per wave
#define RPB  (WPB * RW)          // 20 rows per block
#define BPB  (Qn / RPB)          // 45 blocks per batch
#define NBLK (Bn * BPB)          // 1440 blocks; 6 blocks/CU LDS-cap -> ONE round
#define BLK  256
#define BIGV 100000000.0f
#define NEGINF -3.402823e38f

typedef float f32x4 __attribute__((ext_vector_type(4)));

__global__ __launch_bounds__(BLK) void hungarian_cost_kernel(
    const float* __restrict__ logits,   // [B,Q,C]
    const float* __restrict__ pboxes,   // [B,Q,4] cxcywh
    const float* __restrict__ gboxes,   // [B,Q,4] cxcywh
    const float* __restrict__ area,     // [B,Q]
    const int*   __restrict__ labels,   // [B,Q]
    float* __restrict__ out)            // [B,Q,Q]
{
    // j-side SoA: 4*3.6K (xyxy) + 1.8K (lab+flag) + 7.36K (pm) = 23.6 KB
    // -> 6 blocks/CU -> 1536 block slots >= 1440 -> single residency round.
    __shared__ float s_x0[Qn], s_y0[Qn], s_x1[Qn], s_y1[Qn];
    __shared__ unsigned short s_lab[Qn];      // label | (area<=0 ? 0x8000 : 0)
    __shared__ float s_pm[WPB][RW][Cn];       // per-wave (prob - 1)

    const int blk   = blockIdx.x;
    const int b     = blk / BPB;
    const int rbase = (blk - b * BPB) * RPB;
    const int tid   = threadIdx.x;
    const int w     = tid >> 6;
    const int lane  = tid & 63;

    // ---- stage j-side data (SoA); all global loads happen BEFORE the barrier ----
    {
        const float4* gb4 = (const float4*)(gboxes + (size_t)b * Qn * 4);
        const float*  ga  = area   + (size_t)b * Qn;
        const int*    gl  = labels + (size_t)b * Qn;
        for (int j = tid; j < Qn; j += BLK) {
            float4 cc = gb4[j];
            s_x0[j] = cc.x - 0.5f * cc.z;
            s_y0[j] = cc.y - 0.5f * cc.w;
            s_x1[j] = cc.x + 0.5f * cc.z;
            s_y1[j] = cc.y + 0.5f * cc.w;
            s_lab[j] = (unsigned short)(gl[j] | ((ga[j] > 0.0f) ? 0 : 0x8000));
        }
    }

    // ---- per-wave softmax of RW rows + pred-box state in registers ----
    float px0[RW], py0[RW], px1[RW], py1[RW], pw[RW], ph[RW], pa[RW];
    const int r0 = rbase + w * RW;
    {
        const float4* pb4 = (const float4*)(pboxes + (size_t)b * Qn * 4);
        #pragma unroll
        for (int m = 0; m < RW; ++m) {
            const int r = r0 + m;
            const float* lrow = logits + ((size_t)b * Qn + r) * Cn;
            float e0 = __expf(lrow[lane]);                      // lane < 64 < 92
            float e1 = (lane < Cn - 64) ? __expf(lrow[lane + 64]) : 0.0f;
            float s = e0 + e1;
            #pragma unroll
            for (int off = 32; off; off >>= 1)
                s += __shfl_xor(s, off);
            float inv = __builtin_amdgcn_rcpf(s);
            s_pm[w][m][lane] = __builtin_fmaf(e0, inv, -1.0f);  // store prob-1
            if (lane < Cn - 64) s_pm[w][m][lane + 64] = __builtin_fmaf(e1, inv, -1.0f);
            float4 c = pb4[r];
            px0[m] = c.x - 0.5f * c.z;
            py0[m] = c.y - 0.5f * c.w;
            px1[m] = c.x + 0.5f * c.z;
            py1[m] = c.y + 0.5f * c.w;
            pw[m]  = c.z;  ph[m] = c.w;  pa[m] = c.z * c.w;
        }
    }
    __syncthreads();   // only barrier; after this NO global loads

    // ---- sweep, SEQUENTIAL store order: m OUTER, t INNER ----
    // Each wave's store addresses strictly increase: row r0+m bytes 0..3600,
    // rows contiguous -> 18 KB fully sequential per wave (was 20 interleaved
    // 1KB bursts across 5 rows in R15). Tier data re-read from LDS per (m,t):
    // conflict-free stride-16B b128 reads, hidden by 24 waves/CU.
    float* ob = out + ((size_t)b * Qn + r0) * Qn;
    #pragma unroll
    for (int m = 0; m < RW; ++m) {
        float* orow = ob + (size_t)m * Qn;
        #pragma unroll
        for (int t = 0; t < 4; ++t) {
            const int jg = lane + 64 * t;            // j-group of 4
            if (t < 3 || lane < 33) {                // t=3: jg = 192..224
                const int j4 = jg * 4;
                const f32x4 X0 = *(const f32x4*)&s_x0[j4];
                const f32x4 Y0 = *(const f32x4*)&s_y0[j4];
                const f32x4 X1 = *(const f32x4*)&s_x1[j4];
                const f32x4 Y1 = *(const f32x4*)&s_y1[j4];
                const ushort4 LBv = *(const ushort4*)&s_lab[j4];

                float res[4];
                #pragma unroll
                for (int k = 0; k < 4; ++k) {
                    const float x0 = X0[k], y0 = Y0[k], x1 = X1[k], y1 = Y1[k];
                    const unsigned short lw = (k==0)?LBv.x:(k==1)?LBv.y:(k==2)?LBv.z:LBv.w;
                    const int   lb = lw & 0x7FFF;
                    const float fl = (lw & 0x8000) ? BIGV : NEGINF;
                    const float pm = s_pm[w][m][lb];     // wave-local gather

                    // mean-L1 in cxcywh from xyxy diffs
                    float dx0 = px0[m] - x0, dy0 = py0[m] - y0;
                    float dx1 = px1[m] - x1, dy1 = py1[m] - y1;
                    float s1 = fabsf(dx0 + dx1) + fabsf(dy0 + dy1);
                    float s2 = fabsf(dx1 - dx0) + fabsf(dy1 - dy0);
                    float bb = __builtin_fmaf(s1, 0.125f, 0.25f * s2);
                    // intersection (raw)
                    float iwr = fminf(px1[m], x1) - fmaxf(px0[m], x0);
                    float ihr = fminf(py1[m], y1) - fmaxf(py0[m], y0);
                    float inter = fmaxf(iwr, 0.0f) * fmaxf(ihr, 0.0f);
                    float uni = (pa[m] + (x1 - x0) * (y1 - y0)) - inter;
                    // enclosing box via min+max=sum identity
                    float ew = (pw[m] + (x1 - x0)) - iwr;
                    float eh = (ph[m] + (y1 - y0)) - ihr;
                    float enc = ew * eh;
                    // single-rcp GIoU: inter/uni + uni/enc = (inter*enc + uni^2)/(uni*enc)
                    float num = __builtin_fmaf(uni, uni, inter * enc);
                    float g = __builtin_fmaf(num, __builtin_amdgcn_rcpf(uni * enc), pm);
                    res[k] = fmaxf(bb - g, fl);
                }
                f32x4 v = { res[0], res[1], res[2], res[3] };
                __builtin_nontemporal_store(v, (f32x4*)(orow + j4));
            }
        }
    }
}

extern "C" void kernel_launch(void* const* d_in, const int* in_sizes, int n_in,
                              void* d_out, int out_size, void* d_ws, size_t ws_size,
                              hipStream_t stream) {
    const float* logits = (const float*)d_in[0];  // pred_logits [B,Q,C]
    const float* pboxes = (const float*)d_in[1];  // pred_boxes  [B,Q,4]
    const float* gboxes = (const float*)d_in[2];  // boxes       [B,Q,4]
    const float* areas  = (const float*)d_in[3];  // area        [B,Q]
    const int*   labels = (const int*)d_in[4];    // labels      [B,Q]
    float* out = (float*)d_out;                   // [B,Q,Q] f32

    hungarian_cost_kernel<<<NBLK, BLK, 0, stream>>>(
        logits, pboxes, gboxes, areas, labels, out);
}